// Round 8
// baseline (184.473 us; speedup 1.0000x reference)
//
#include <hip/hip_runtime.h>
#include <hip/hip_bf16.h>

#define B_DIM 64
#define T_DIM 512
#define H_DIM 1024

typedef __attribute__((ext_vector_type(4))) float f32x4;

// ws layout (bytes)
#define AQ8_OFF  0UL              // A' fp8 frag-major: 32768*1024 = 33554432
#define BQ8_OFF  33554432UL       // B' fp8 frag-major: 1024*1024  =  1048576
#define DEC_OFF  34603008UL       // 64*1024*4  =  262144
#define PART_OFF 34865152UL       // 32768*8*4  = 1048576
#define AT_OFF   35913728UL       // 32768*4    =  131072
// total 36044800 bytes

// ---- OCP e4m3fn encode (RNE, satfinite) / decode — self-consistent pair ----
__device__ __forceinline__ unsigned char f2e4m3(float x) {
  float a = fabsf(x);
  unsigned s = (__float_as_uint(x) >> 31) << 7;
  a = fminf(a, 448.0f);
  unsigned char r;
  if (a < 0.015625f) {                       // subnormal: m * 2^-9
    int mi = (int)rintf(a * 512.0f);         // 0..8
    r = (unsigned char)mi;                   // mi==8 -> 0x08 == 2^-6 (e=1,m=0)
  } else {
    int ep = (int)(__float_as_uint(a) >> 23) - 127;          // -6..8
    float scale = __uint_as_float((unsigned)(130 - ep) << 23); // 2^(3-ep)
    int mi = (int)rintf(a * scale);          // 8..16
    if (mi == 16) { mi = 8; ep++; }
    r = (unsigned char)(((ep + 7) << 3) | (mi - 8));
  }
  return (unsigned char)(r | s);
}
__device__ __forceinline__ float e4m3f(unsigned char v) {
  unsigned e = (v >> 3) & 15u, m = v & 7u;
  float mag = (e == 0) ? (float)m * 0.001953125f
                       : (float)(8 + m) * __uint_as_float((e + 117u) << 23);
  return (v & 0x80u) ? -mag : mag;
}

__device__ __forceinline__ void gload_lds16(const void* g, void* l) {
  __builtin_amdgcn_global_load_lds(
      (const __attribute__((address_space(1))) void*)g,
      (__attribute__((address_space(3))) void*)l, 16, 0, 0);
}

// Fragment-major fp8 layout (16x16x32 MFMA frags):
// frag(mt,kt) = 512B at ((mt*32)+kt)*512; lane l holds X[row=mt*16+(l&15)]
// [k = kt*32 + (l>>4)*8 + j], j=0..7.

// K1: prep — all GLOBAL accesses coalesced; layout permutation via LDS.
// blocks 0..2047: A m-tiles (16 rows x 1024): read prev, write concat copy,
//   write fp8*4 frags. blocks 2048..2111: B n-tiles (W_prev, fp8*16 frags).
// block 2112: s_t -> concat tail rows.
__global__ __launch_bounds__(256, 8) void prep_ws(
    const float* __restrict__ prev,
    const float* __restrict__ st,
    const float* __restrict__ Wp,
    float* __restrict__ out,
    unsigned char* __restrict__ Aq,
    unsigned char* __restrict__ Bq) {
  __shared__ unsigned char lq[16][264];   // padded: row stride 66 dwords
  int bid = blockIdx.x;
  int tid = threadIdx.x;
  int w = tid >> 6, lane = tid & 63;

  if (bid < 2048) {                       // ---- A-tile ----
    int mt = bid;
    int b = mt >> 5;                      // 32 m-tiles per batch
    int t0 = (mt & 31) * 16;
    const float4* src4 = (const float4*)prev + (size_t)mt * 4096;
    float4* dst4 = (float4*)out + 16384 + (size_t)b * 131328 + (size_t)t0 * 256;
    #pragma unroll
    for (int cc = 0; cc < 4; cc++) {
      #pragma unroll
      for (int p = 0; p < 4; p++) {
        int idx = p * 256 + tid;          // 0..1023
        int row = idx >> 6, cg = idx & 63;
        size_t o = (size_t)row * 256 + cc * 64 + cg;
        float4 f = src4[o];
        dst4[o] = f;
        uchar4 q;
        q.x = f2e4m3(f.x * 4.f); q.y = f2e4m3(f.y * 4.f);
        q.z = f2e4m3(f.z * 4.f); q.w = f2e4m3(f.w * 4.f);
        *(uchar4*)&lq[row][cg * 4] = q;
      }
      __syncthreads();
      #pragma unroll
      for (int q = 0; q < 2; q++) {
        int ktl = w * 2 + q;              // 0..7
        int kt = cc * 8 + ktl;
        uint2 val = *(const uint2*)&lq[lane & 15][ktl * 32 + (lane >> 4) * 8];
        *(uint2*)(Aq + ((size_t)mt * 32 + kt) * 512 + (size_t)lane * 8) = val;
      }
      __syncthreads();
    }
  } else if (bid < 2112) {                // ---- B-tile (W_prev) ----
    int nt = bid - 2048;
    const float4* src4 = (const float4*)Wp + (size_t)nt * 4096;
    #pragma unroll
    for (int cc = 0; cc < 4; cc++) {
      #pragma unroll
      for (int p = 0; p < 4; p++) {
        int idx = p * 256 + tid;
        int row = idx >> 6, cg = idx & 63;
        float4 f = src4[(size_t)row * 256 + cc * 64 + cg];
        uchar4 q;
        q.x = f2e4m3(f.x * 16.f); q.y = f2e4m3(f.y * 16.f);
        q.z = f2e4m3(f.z * 16.f); q.w = f2e4m3(f.w * 16.f);
        *(uchar4*)&lq[row][cg * 4] = q;
      }
      __syncthreads();
      #pragma unroll
      for (int q = 0; q < 2; q++) {
        int ktl = w * 2 + q;
        int kt = cc * 8 + ktl;
        uint2 val = *(const uint2*)&lq[lane & 15][ktl * 32 + (lane >> 4) * 8];
        *(uint2*)(Bq + ((size_t)nt * 32 + kt) * 512 + (size_t)lane * 8) = val;
      }
      __syncthreads();
    }
  } else {                                // ---- s_t tail rows ----
    const float4* s4 = (const float4*)st;
    for (int b = 0; b < B_DIM; b++) {
      float4* o4 = (float4*)out + 16384 + (size_t)b * 131328 + 131072;
      o4[tid] = s4[(size_t)b * 256 + tid];
    }
  }
}

// K2: dec_fea[b][o] = sum_h s_t[b][h]*W_s[o][h] + b_s[o]
__global__ void dec_kernel(const float* __restrict__ st,
                           const float* __restrict__ Ws,
                           const float* __restrict__ bs,
                           float* __restrict__ dec) {
  int tid = threadIdx.x;
  int lane = tid & 63, w = tid >> 6;
  int o = blockIdx.x * 4 + w;
  const float4* wrow = (const float4*)(Ws + (size_t)o * H_DIM);
  float4 w0 = wrow[lane], w1 = wrow[64 + lane], w2 = wrow[128 + lane], w3 = wrow[192 + lane];
  const float4* st4 = (const float4*)st;
  float bias = bs[o];
  #pragma unroll 8
  for (int b = 0; b < B_DIM; b++) {
    const float4* s = st4 + (size_t)b * 256;
    float4 s0 = s[lane], s1 = s[64 + lane], s2 = s[128 + lane], s3 = s[192 + lane];
    float p = w0.x * s0.x + w0.y * s0.y + w0.z * s0.z + w0.w * s0.w
            + w1.x * s1.x + w1.y * s1.y + w1.z * s1.z + w1.w * s1.w
            + w2.x * s2.x + w2.y * s2.y + w2.z * s2.z + w2.w * s2.w
            + w3.x * s3.x + w3.y * s3.y + w3.z * s3.z + w3.w * s3.w;
    p += __shfl_xor(p, 1);  p += __shfl_xor(p, 2);
    p += __shfl_xor(p, 4);  p += __shfl_xor(p, 8);
    p += __shfl_xor(p, 16); p += __shfl_xor(p, 32);
    if (lane == 0) dec[(size_t)b * H_DIM + o] = p + bias;
  }
}

// K3: fp8 score GEMM. 128x128 block, 2x2 waves of 64x64, BK=64,
// fragment-major LDS (linear stage, conflict-free ds_read_b64),
// raw-barrier + counted-vmcnt(4). acc = 64*et.
__global__ __launch_bounds__(256, 3) void score_gemm(
    const unsigned char* __restrict__ Aq,
    const unsigned char* __restrict__ Bq,
    const float* __restrict__ dec,
    const float* __restrict__ v,
    float* __restrict__ part)
{
  __shared__ __align__(16) unsigned char ldsA[2][8192];
  __shared__ __align__(16) unsigned char ldsB[2][8192];

  int orig = blockIdx.x;                       // 2048 blocks
  int swz = (orig & 7) * 256 + (orig >> 3);    // bijective XCD swizzle
  int bm = swz >> 3, bn = swz & 7;

  int tid = threadIdx.x;
  int lane = tid & 63, w = tid >> 6;
  int wm = w >> 1, wn = w & 1;                 // 2x2 waves, 64x64 each
  size_t m0 = (size_t)bm * 128;

  f32x4 acc[4][4];
  #pragma unroll
  for (int i = 0; i < 4; i++)
    #pragma unroll
    for (int j = 0; j < 4; j++) {
      f32x4 z; z.x = 0.f; z.y = 0.f; z.z = 0.f; z.w = 0.f;
      acc[i][j] = z;
    }

  int fA = tid >> 5, cif = tid & 31;
  const unsigned char* aSrc0 =
      Aq + ((size_t)(bm * 8 + (fA >> 1)) * 32 + (fA & 1)) * 512 + (size_t)cif * 16;
  const unsigned char* aSrc1 =
      Aq + ((size_t)(bm * 8 + (fA >> 1) + 4) * 32 + (fA & 1)) * 512 + (size_t)cif * 16;
  const unsigned char* bSrc0 =
      Bq + ((size_t)(bn * 8 + (fA >> 1)) * 32 + (fA & 1)) * 512 + (size_t)cif * 16;
  const unsigned char* bSrc1 =
      Bq + ((size_t)(bn * 8 + (fA >> 1) + 4) * 32 + (fA & 1)) * 512 + (size_t)cif * 16;

#define STAGE(buf, t) do { \
    size_t ko = (size_t)(t) * 1024; \
    gload_lds16(aSrc0 + ko, &ldsA[(buf)][tid * 16]); \
    gload_lds16(aSrc1 + ko, &ldsA[(buf)][tid * 16 + 4096]); \
    gload_lds16(bSrc0 + ko, &ldsB[(buf)][tid * 16]); \
    gload_lds16(bSrc1 + ko, &ldsB[(buf)][tid * 16 + 4096]); \
  } while (0)

  STAGE(0, 0);

  #pragma unroll 2
  for (int t = 0; t < 16; t++) {
    int cur = t & 1, nxt = cur ^ 1;
    if (t < 15) {
      STAGE(nxt, t + 1);
      asm volatile("s_waitcnt vmcnt(4)" ::: "memory");
    } else {
      asm volatile("s_waitcnt vmcnt(0)" ::: "memory");
    }
    __builtin_amdgcn_s_barrier();
    asm volatile("" ::: "memory");

    const unsigned char* Ac = &ldsA[cur][0];
    const unsigned char* Bc = &ldsB[cur][0];
    long av[4][2], bv[4][2];
    #pragma unroll
    for (int mf = 0; mf < 4; mf++)
      #pragma unroll
      for (int kk = 0; kk < 2; kk++)
        av[mf][kk] = *(const long*)(Ac + ((wm * 4 + mf) * 2 + kk) * 512 + lane * 8);
    #pragma unroll
    for (int nf = 0; nf < 4; nf++)
      #pragma unroll
      for (int kk = 0; kk < 2; kk++)
        bv[nf][kk] = *(const long*)(Bc + ((wn * 4 + nf) * 2 + kk) * 512 + lane * 8);

    __builtin_amdgcn_s_setprio(1);
    #pragma unroll
    for (int kk = 0; kk < 2; kk++)
      #pragma unroll
      for (int mf = 0; mf < 4; mf++)
        #pragma unroll
        for (int nf = 0; nf < 4; nf++)
          acc[mf][nf] = __builtin_amdgcn_mfma_f32_16x16x32_fp8_fp8(
              av[mf][kk], bv[nf][kk], acc[mf][nf], 0, 0, 0);
    __builtin_amdgcn_s_setprio(0);
    asm volatile("" ::: "memory");
    __builtin_amdgcn_s_barrier();
  }
#undef STAGE

  // epilogue: x = acc/64 + dec; tanh; dot v; 16-col shfl reduce; wn-pair via LDS
  int b = (int)(m0 >> 9);
  int lr = lane >> 4, lc = lane & 15;
  int n0 = bn * 128;
  float dv[4], vv[4];
  #pragma unroll
  for (int nf = 0; nf < 4; nf++) {
    int col = n0 + wn * 64 + nf * 16 + lc;
    dv[nf] = dec[(size_t)b * H_DIM + col];
    vv[nf] = v[col];
  }
  float* epi = (float*)&ldsA[0][0];  // [128 rows][2 wn] floats = 1KB
  #pragma unroll
  for (int mf = 0; mf < 4; mf++) {
    #pragma unroll
    for (int r = 0; r < 4; r++) {
      float s = 0.f;
      #pragma unroll
      for (int nf = 0; nf < 4; nf++) {
        float x = acc[mf][nf][r] * 0.015625f + dv[nf];
        x = fminf(fmaxf(x, -15.f), 15.f);
        float e = __expf(2.f * x);
        s += vv[nf] * (e - 1.f) * __builtin_amdgcn_rcpf(e + 1.f);
      }
      s += __shfl_xor(s, 1); s += __shfl_xor(s, 2);
      s += __shfl_xor(s, 4); s += __shfl_xor(s, 8);
      if (lc == 0) epi[(wm * 64 + mf * 16 + lr * 4 + r) * 2 + wn] = s;
    }
  }
  __syncthreads();
  if (tid < 128) {
    part[(m0 + tid) * 8 + bn] = epi[tid * 2] + epi[tid * 2 + 1];
  }
}

// K4: softmax over T per batch row (8 partials per row)
__global__ void softmax_kernel(const float* __restrict__ part, float* __restrict__ at) {
  int b = blockIdx.x, tid = threadIdx.x;
  __shared__ float sc[512];
  __shared__ float red[8];
  #pragma unroll
  for (int rep = 0; rep < 2; rep++) {
    int t = rep * 256 + tid;
    const float* p = part + ((size_t)b * 512 + t) * 8;
    sc[t] = p[0] + p[1] + p[2] + p[3] + p[4] + p[5] + p[6] + p[7];
  }
  __syncthreads();
  float m = fmaxf(sc[tid], sc[tid + 256]);
  for (int d = 1; d < 64; d <<= 1) m = fmaxf(m, __shfl_xor(m, d));
  if ((tid & 63) == 0) red[tid >> 6] = m;
  __syncthreads();
  m = fmaxf(fmaxf(red[0], red[1]), fmaxf(red[2], red[3]));
  float e0 = __expf(sc[tid] - m), e1 = __expf(sc[tid + 256] - m);
  float s = e0 + e1;
  for (int d = 1; d < 64; d <<= 1) s += __shfl_xor(s, d);
  if ((tid & 63) == 0) red[4 + (tid >> 6)] = s;
  __syncthreads();
  s = red[4] + red[5] + red[6] + red[7];
  float inv = 1.f / s;
  at[(size_t)b * 512 + tid] = e0 * inv;
  at[(size_t)b * 512 + tid + 256] = e1 * inv;
}

// K5: ct_d[b][h] = sum_t at[b][t] * prev[b][t][h] from fp8 frag-major A'
// (values are 4x -> scale 0.25). One wave per (b, kt): in-wave reduction.
__global__ void ctd_ws(const unsigned char* __restrict__ Aq,
                       const float* __restrict__ at, float* __restrict__ out) {
  int wid = blockIdx.x * 4 + (threadIdx.x >> 6);  // 2048 = 64 b x 32 kt
  int lane = threadIdx.x & 63;
  int b = wid >> 5, kt = wid & 31;
  int lc = lane & 15, lr = lane >> 4;
  float a8[8] = {0.f, 0.f, 0.f, 0.f, 0.f, 0.f, 0.f, 0.f};
  const unsigned char* base =
      Aq + ((size_t)b * 32 * 32 + kt) * 512 + (size_t)lane * 8;
  const float* atb = at + (size_t)b * 512;
  #pragma unroll 8
  for (int mt = 0; mt < 32; mt++) {
    float a = atb[mt * 16 + lc];
    uint2 uv = *(const uint2*)(base + (size_t)mt * 16384);
    unsigned char* q = (unsigned char*)&uv;
    #pragma unroll
    for (int j = 0; j < 8; j++) a8[j] += a * e4m3f(q[j]);
  }
  #pragma unroll
  for (int d = 1; d < 16; d <<= 1)
    #pragma unroll
    for (int j = 0; j < 8; j++) a8[j] += __shfl_xor(a8[j], d);
  if (lc == 0) {
    #pragma unroll
    for (int j = 0; j < 8; j++)
      out[(size_t)b * H_DIM + kt * 32 + lr * 8 + j] = a8[j] * 0.25f;
  }
}

extern "C" void kernel_launch(void* const* d_in, const int* in_sizes, int n_in,
                              void* d_out, int out_size, void* d_ws, size_t ws_size,
                              hipStream_t stream) {
  (void)in_sizes; (void)n_in; (void)out_size; (void)ws_size;
  const float* s_t    = (const float*)d_in[0];
  const float* prev_s = (const float*)d_in[1];
  const float* W_prev = (const float*)d_in[2];
  const float* W_s    = (const float*)d_in[3];
  const float* b_s    = (const float*)d_in[4];
  const float* v      = (const float*)d_in[5];
  float* out = (float*)d_out;
  char* ws = (char*)d_ws;

  unsigned char* Aq = (unsigned char*)(ws + AQ8_OFF);
  unsigned char* Bq = (unsigned char*)(ws + BQ8_OFF);
  float* dec  = (float*)(ws + DEC_OFF);
  float* part = (float*)(ws + PART_OFF);
  float* at   = (float*)(ws + AT_OFF);

  prep_ws<<<2113, 256, 0, stream>>>(prev_s, s_t, W_prev, out, Aq, Bq);
  dec_kernel<<<256, 256, 0, stream>>>(s_t, W_s, b_s, dec);
  score_gemm<<<2048, 256, 0, stream>>>(Aq, Bq, dec, v, part);
  softmax_kernel<<<64, 256, 0, stream>>>(part, at);
  ctd_ws<<<512, 256, 0, stream>>>(Aq, at, out);
}

// Round 9
// 181.364 us; speedup vs baseline: 1.0171x; 1.0171x over previous
//
#include <hip/hip_runtime.h>
#include <hip/hip_bf16.h>

#define B_DIM 64
#define T_DIM 512
#define H_DIM 1024

typedef __attribute__((ext_vector_type(4))) float f32x4;

// ws layout (bytes)
#define AQ8_OFF  0UL              // A' fp8 frag-major: 32768*1024 = 33554432
#define BQ8_OFF  33554432UL       // B' fp8 frag-major: 1024*1024  =  1048576
#define DEC_OFF  34603008UL       // 64*1024*4  =  262144
#define PART_OFF 34865152UL       // 32768*8*4  = 1048576
#define AT_OFF   35913728UL       // 32768*4    =  131072
// total 36044800 bytes

// ---- OCP e4m3fn encode (RNE, satfinite) / decode — self-consistent pair ----
__device__ __forceinline__ unsigned char f2e4m3(float x) {
  float a = fabsf(x);
  unsigned s = (__float_as_uint(x) >> 31) << 7;
  a = fminf(a, 448.0f);
  unsigned char r;
  if (a < 0.015625f) {                       // subnormal: m * 2^-9
    int mi = (int)rintf(a * 512.0f);         // 0..8
    r = (unsigned char)mi;                   // mi==8 -> 0x08 == 2^-6 (e=1,m=0)
  } else {
    int ep = (int)(__float_as_uint(a) >> 23) - 127;          // -6..8
    float scale = __uint_as_float((unsigned)(130 - ep) << 23); // 2^(3-ep)
    int mi = (int)rintf(a * scale);          // 8..16
    if (mi == 16) { mi = 8; ep++; }
    r = (unsigned char)(((ep + 7) << 3) | (mi - 8));
  }
  return (unsigned char)(r | s);
}
__device__ __forceinline__ float e4m3f(unsigned char v) {
  unsigned e = (v >> 3) & 15u, m = v & 7u;
  float mag = (e == 0) ? (float)m * 0.001953125f
                       : (float)(8 + m) * __uint_as_float((e + 117u) << 23);
  return (v & 0x80u) ? -mag : mag;
}

__device__ __forceinline__ void gload_lds16(const void* g, void* l) {
  __builtin_amdgcn_global_load_lds(
      (const __attribute__((address_space(1))) void*)g,
      (__attribute__((address_space(3))) void*)l, 16, 0, 0);
}

// Fragment-major fp8 layout (16x16x32 MFMA frags):
// frag(mt,kt) = 512B at ((mt*32)+kt)*512; lane l holds X[row=mt*16+(l&15)]
// [k = kt*32 + (l>>4)*8 + j], j=0..7.

// K1: prep v3 — deep-ILP, 2 barriers/block, ping-pong LDS transpose.
// blocks 0..2047: A m-tiles (16 rows x 1024). 2048..2111: B n-tiles.
// 2112: s_t tail.  All global accesses >=128B-segment coalesced.
__global__ __launch_bounds__(256) void prep_ws(
    const float* __restrict__ prev,
    const float* __restrict__ st,
    const float* __restrict__ Wp,
    float* __restrict__ out,
    unsigned char* __restrict__ Aq,
    unsigned char* __restrict__ Bq) {
  __shared__ unsigned char lq[2][16][528];   // 528 = 512 + 16 pad (2-way banks)
  int bid = blockIdx.x;
  int tid = threadIdx.x;

  if (bid < 2112) {
    bool isA = bid < 2048;
    int mt = isA ? bid : bid - 2048;
    const float4* src4 =
        (const float4*)(isA ? prev : Wp) + (size_t)mt * 4096;
    float4* dst4 = nullptr;
    if (isA) {
      int b = mt >> 5, t0 = (mt & 31) * 16;
      dst4 = (float4*)out + 16384 + (size_t)b * 131328 + (size_t)t0 * 256;
    }
    unsigned char* q8 = (isA ? Aq : Bq) + (size_t)mt * 16384;  // 32 frags
    float scale = isA ? 4.f : 16.f;

    int row = tid >> 5;                // thread's fixed row (0..15) per p-step? no:
    // mapping: idx = p*256+tid -> row = idx>>7, cg = idx&127 (see loops)

    float4 buf[8];
    // ---- issue all 8 loads of half 0 (independent; ~32 VGPRs in flight) ----
    #pragma unroll
    for (int p = 0; p < 8; p++) {
      int idx = p * 256 + tid;
      int r = idx >> 7, cg = idx & 127;
      buf[p] = src4[(size_t)r * 256 + cg];
    }
    // ---- consume half 0: concat copy + fp8 -> LDS[0] ----
    #pragma unroll
    for (int p = 0; p < 8; p++) {
      int idx = p * 256 + tid;
      int r = idx >> 7, cg = idx & 127;
      if (isA) dst4[(size_t)r * 256 + cg] = buf[p];
      uchar4 q;
      q.x = f2e4m3(buf[p].x * scale); q.y = f2e4m3(buf[p].y * scale);
      q.z = f2e4m3(buf[p].z * scale); q.w = f2e4m3(buf[p].w * scale);
      *(uchar4*)&lq[0][r][cg * 4] = q;
    }
    // ---- issue all 8 loads of half 1 (stay in flight across barrier) ----
    #pragma unroll
    for (int p = 0; p < 8; p++) {
      int idx = p * 256 + tid;
      int r = idx >> 7, cg = idx & 127;
      buf[p] = src4[(size_t)r * 256 + 128 + cg];
    }
    asm volatile("s_waitcnt lgkmcnt(0)" ::: "memory");  // LDS writes visible
    __builtin_amdgcn_s_barrier();

    // ---- gather half 0: 512 chunks -> frag-major stores (1KB/wave) ----
    #pragma unroll
    for (int cc = 0; cc < 2; cc++) {
      int c = cc * 256 + tid;          // 0..511
      int ktl = c >> 5, ci = c & 31;
      int r0 = (2 * ci) & 15, oct = ci >> 3;
      uint2 lo = *(const uint2*)&lq[0][r0][ktl * 32 + oct * 8];
      uint2 hi = *(const uint2*)&lq[0][r0 + 1][ktl * 32 + oct * 8];
      uint4 val = make_uint4(lo.x, lo.y, hi.x, hi.y);
      *(uint4*)(q8 + (size_t)ktl * 512 + ci * 16) = val;
    }
    // ---- consume half 1 (compiler waits vmcnt on buf use) -> LDS[1] ----
    #pragma unroll
    for (int p = 0; p < 8; p++) {
      int idx = p * 256 + tid;
      int r = idx >> 7, cg = idx & 127;
      if (isA) dst4[(size_t)r * 256 + 128 + cg] = buf[p];
      uchar4 q;
      q.x = f2e4m3(buf[p].x * scale); q.y = f2e4m3(buf[p].y * scale);
      q.z = f2e4m3(buf[p].z * scale); q.w = f2e4m3(buf[p].w * scale);
      *(uchar4*)&lq[1][r][cg * 4] = q;
    }
    asm volatile("s_waitcnt lgkmcnt(0)" ::: "memory");
    __builtin_amdgcn_s_barrier();

    // ---- gather half 1 (kt 16..31) ----
    #pragma unroll
    for (int cc = 0; cc < 2; cc++) {
      int c = cc * 256 + tid;
      int ktl = c >> 5, ci = c & 31;
      int r0 = (2 * ci) & 15, oct = ci >> 3;
      uint2 lo = *(const uint2*)&lq[1][r0][ktl * 32 + oct * 8];
      uint2 hi = *(const uint2*)&lq[1][r0 + 1][ktl * 32 + oct * 8];
      uint4 val = make_uint4(lo.x, lo.y, hi.x, hi.y);
      *(uint4*)(q8 + (size_t)(16 + ktl) * 512 + ci * 16) = val;
    }
  } else {                                // ---- s_t tail rows ----
    const float4* s4 = (const float4*)st;
    for (int b = 0; b < B_DIM; b++) {
      float4* o4 = (float4*)out + 16384 + (size_t)b * 131328 + 131072;
      o4[tid] = s4[(size_t)b * 256 + tid];
    }
  }
}

// K2: dec_fea[b][o] = sum_h s_t[b][h]*W_s[o][h] + b_s[o]
__global__ void dec_kernel(const float* __restrict__ st,
                           const float* __restrict__ Ws,
                           const float* __restrict__ bs,
                           float* __restrict__ dec) {
  int tid = threadIdx.x;
  int lane = tid & 63, w = tid >> 6;
  int o = blockIdx.x * 4 + w;
  const float4* wrow = (const float4*)(Ws + (size_t)o * H_DIM);
  float4 w0 = wrow[lane], w1 = wrow[64 + lane], w2 = wrow[128 + lane], w3 = wrow[192 + lane];
  const float4* st4 = (const float4*)st;
  float bias = bs[o];
  #pragma unroll 8
  for (int b = 0; b < B_DIM; b++) {
    const float4* s = st4 + (size_t)b * 256;
    float4 s0 = s[lane], s1 = s[64 + lane], s2 = s[128 + lane], s3 = s[192 + lane];
    float p = w0.x * s0.x + w0.y * s0.y + w0.z * s0.z + w0.w * s0.w
            + w1.x * s1.x + w1.y * s1.y + w1.z * s1.z + w1.w * s1.w
            + w2.x * s2.x + w2.y * s2.y + w2.z * s2.z + w2.w * s2.w
            + w3.x * s3.x + w3.y * s3.y + w3.z * s3.z + w3.w * s3.w;
    p += __shfl_xor(p, 1);  p += __shfl_xor(p, 2);
    p += __shfl_xor(p, 4);  p += __shfl_xor(p, 8);
    p += __shfl_xor(p, 16); p += __shfl_xor(p, 32);
    if (lane == 0) dec[(size_t)b * H_DIM + o] = p + bias;
  }
}

// K3: fp8 score GEMM. 128x128 block, 2x2 waves of 64x64, BK=64,
// fragment-major LDS (linear stage, conflict-free ds_read_b64),
// raw-barrier + counted-vmcnt(4). acc = 64*et.
__global__ __launch_bounds__(256, 3) void score_gemm(
    const unsigned char* __restrict__ Aq,
    const unsigned char* __restrict__ Bq,
    const float* __restrict__ dec,
    const float* __restrict__ v,
    float* __restrict__ part)
{
  __shared__ __align__(16) unsigned char ldsA[2][8192];
  __shared__ __align__(16) unsigned char ldsB[2][8192];

  int orig = blockIdx.x;                       // 2048 blocks
  int swz = (orig & 7) * 256 + (orig >> 3);    // bijective XCD swizzle
  int bm = swz >> 3, bn = swz & 7;

  int tid = threadIdx.x;
  int lane = tid & 63, w = tid >> 6;
  int wm = w >> 1, wn = w & 1;                 // 2x2 waves, 64x64 each
  size_t m0 = (size_t)bm * 128;

  f32x4 acc[4][4];
  #pragma unroll
  for (int i = 0; i < 4; i++)
    #pragma unroll
    for (int j = 0; j < 4; j++) {
      f32x4 z; z.x = 0.f; z.y = 0.f; z.z = 0.f; z.w = 0.f;
      acc[i][j] = z;
    }

  int fA = tid >> 5, cif = tid & 31;
  const unsigned char* aSrc0 =
      Aq + ((size_t)(bm * 8 + (fA >> 1)) * 32 + (fA & 1)) * 512 + (size_t)cif * 16;
  const unsigned char* aSrc1 =
      Aq + ((size_t)(bm * 8 + (fA >> 1) + 4) * 32 + (fA & 1)) * 512 + (size_t)cif * 16;
  const unsigned char* bSrc0 =
      Bq + ((size_t)(bn * 8 + (fA >> 1)) * 32 + (fA & 1)) * 512 + (size_t)cif * 16;
  const unsigned char* bSrc1 =
      Bq + ((size_t)(bn * 8 + (fA >> 1) + 4) * 32 + (fA & 1)) * 512 + (size_t)cif * 16;

#define STAGE(buf, t) do { \
    size_t ko = (size_t)(t) * 1024; \
    gload_lds16(aSrc0 + ko, &ldsA[(buf)][tid * 16]); \
    gload_lds16(aSrc1 + ko, &ldsA[(buf)][tid * 16 + 4096]); \
    gload_lds16(bSrc0 + ko, &ldsB[(buf)][tid * 16]); \
    gload_lds16(bSrc1 + ko, &ldsB[(buf)][tid * 16 + 4096]); \
  } while (0)

  STAGE(0, 0);

  #pragma unroll 2
  for (int t = 0; t < 16; t++) {
    int cur = t & 1, nxt = cur ^ 1;
    if (t < 15) {
      STAGE(nxt, t + 1);
      asm volatile("s_waitcnt vmcnt(4)" ::: "memory");
    } else {
      asm volatile("s_waitcnt vmcnt(0)" ::: "memory");
    }
    __builtin_amdgcn_s_barrier();
    asm volatile("" ::: "memory");

    const unsigned char* Ac = &ldsA[cur][0];
    const unsigned char* Bc = &ldsB[cur][0];
    long av[4][2], bv[4][2];
    #pragma unroll
    for (int mf = 0; mf < 4; mf++)
      #pragma unroll
      for (int kk = 0; kk < 2; kk++)
        av[mf][kk] = *(const long*)(Ac + ((wm * 4 + mf) * 2 + kk) * 512 + lane * 8);
    #pragma unroll
    for (int nf = 0; nf < 4; nf++)
      #pragma unroll
      for (int kk = 0; kk < 2; kk++)
        bv[nf][kk] = *(const long*)(Bc + ((wn * 4 + nf) * 2 + kk) * 512 + lane * 8);

    __builtin_amdgcn_s_setprio(1);
    #pragma unroll
    for (int kk = 0; kk < 2; kk++)
      #pragma unroll
      for (int mf = 0; mf < 4; mf++)
        #pragma unroll
        for (int nf = 0; nf < 4; nf++)
          acc[mf][nf] = __builtin_amdgcn_mfma_f32_16x16x32_fp8_fp8(
              av[mf][kk], bv[nf][kk], acc[mf][nf], 0, 0, 0);
    __builtin_amdgcn_s_setprio(0);
    asm volatile("" ::: "memory");
    __builtin_amdgcn_s_barrier();
  }
#undef STAGE

  // epilogue: x = acc/64 + dec; tanh; dot v; 16-col shfl reduce; wn-pair via LDS
  int b = (int)(m0 >> 9);
  int lr = lane >> 4, lc = lane & 15;
  int n0 = bn * 128;
  float dv[4], vv[4];
  #pragma unroll
  for (int nf = 0; nf < 4; nf++) {
    int col = n0 + wn * 64 + nf * 16 + lc;
    dv[nf] = dec[(size_t)b * H_DIM + col];
    vv[nf] = v[col];
  }
  float* epi = (float*)&ldsA[0][0];  // [128 rows][2 wn] floats = 1KB
  #pragma unroll
  for (int mf = 0; mf < 4; mf++) {
    #pragma unroll
    for (int r = 0; r < 4; r++) {
      float s = 0.f;
      #pragma unroll
      for (int nf = 0; nf < 4; nf++) {
        float x = acc[mf][nf][r] * 0.015625f + dv[nf];
        x = fminf(fmaxf(x, -15.f), 15.f);
        float e = __expf(2.f * x);
        s += vv[nf] * (e - 1.f) * __builtin_amdgcn_rcpf(e + 1.f);
      }
      s += __shfl_xor(s, 1); s += __shfl_xor(s, 2);
      s += __shfl_xor(s, 4); s += __shfl_xor(s, 8);
      if (lc == 0) epi[(wm * 64 + mf * 16 + lr * 4 + r) * 2 + wn] = s;
    }
  }
  __syncthreads();
  if (tid < 128) {
    part[(m0 + tid) * 8 + bn] = epi[tid * 2] + epi[tid * 2 + 1];
  }
}

// K4: softmax over T per batch row (8 partials per row)
__global__ void softmax_kernel(const float* __restrict__ part, float* __restrict__ at) {
  int b = blockIdx.x, tid = threadIdx.x;
  __shared__ float sc[512];
  __shared__ float red[8];
  #pragma unroll
  for (int rep = 0; rep < 2; rep++) {
    int t = rep * 256 + tid;
    const float* p = part + ((size_t)b * 512 + t) * 8;
    sc[t] = p[0] + p[1] + p[2] + p[3] + p[4] + p[5] + p[6] + p[7];
  }
  __syncthreads();
  float m = fmaxf(sc[tid], sc[tid + 256]);
  for (int d = 1; d < 64; d <<= 1) m = fmaxf(m, __shfl_xor(m, d));
  if ((tid & 63) == 0) red[tid >> 6] = m;
  __syncthreads();
  m = fmaxf(fmaxf(red[0], red[1]), fmaxf(red[2], red[3]));
  float e0 = __expf(sc[tid] - m), e1 = __expf(sc[tid + 256] - m);
  float s = e0 + e1;
  for (int d = 1; d < 64; d <<= 1) s += __shfl_xor(s, d);
  if ((tid & 63) == 0) red[4 + (tid >> 6)] = s;
  __syncthreads();
  s = red[4] + red[5] + red[6] + red[7];
  float inv = 1.f / s;
  at[(size_t)b * 512 + tid] = e0 * inv;
  at[(size_t)b * 512 + tid + 256] = e1 * inv;
}

// K5: ct_d[b][h] = sum_t at[b][t] * prev[b][t][h] from fp8 frag-major A'
// (values are 4x -> scale 0.25). One wave per (b, kt): in-wave reduction.
__global__ void ctd_ws(const unsigned char* __restrict__ Aq,
                       const float* __restrict__ at, float* __restrict__ out) {
  int wid = blockIdx.x * 4 + (threadIdx.x >> 6);  // 2048 = 64 b x 32 kt
  int lane = threadIdx.x & 63;
  int b = wid >> 5, kt = wid & 31;
  int lc = lane & 15, lr = lane >> 4;
  float a8[8] = {0.f, 0.f, 0.f, 0.f, 0.f, 0.f, 0.f, 0.f};
  const unsigned char* base =
      Aq + ((size_t)b * 32 * 32 + kt) * 512 + (size_t)lane * 8;
  const float* atb = at + (size_t)b * 512;
  #pragma unroll 8
  for (int mt = 0; mt < 32; mt++) {
    float a = atb[mt * 16 + lc];
    uint2 uv = *(const uint2*)(base + (size_t)mt * 16384);
    unsigned char* q = (unsigned char*)&uv;
    #pragma unroll
    for (int j = 0; j < 8; j++) a8[j] += a * e4m3f(q[j]);
  }
  #pragma unroll
  for (int d = 1; d < 16; d <<= 1)
    #pragma unroll
    for (int j = 0; j < 8; j++) a8[j] += __shfl_xor(a8[j], d);
  if (lc == 0) {
    #pragma unroll
    for (int j = 0; j < 8; j++)
      out[(size_t)b * H_DIM + kt * 32 + lr * 8 + j] = a8[j] * 0.25f;
  }
}

extern "C" void kernel_launch(void* const* d_in, const int* in_sizes, int n_in,
                              void* d_out, int out_size, void* d_ws, size_t ws_size,
                              hipStream_t stream) {
  (void)in_sizes; (void)n_in; (void)out_size; (void)ws_size;
  const float* s_t    = (const float*)d_in[0];
  const float* prev_s = (const float*)d_in[1];
  const float* W_prev = (const float*)d_in[2];
  const float* W_s    = (const float*)d_in[3];
  const float* b_s    = (const float*)d_in[4];
  const float* v      = (const float*)d_in[5];
  float* out = (float*)d_out;
  char* ws = (char*)d_ws;

  unsigned char* Aq = (unsigned char*)(ws + AQ8_OFF);
  unsigned char* Bq = (unsigned char*)(ws + BQ8_OFF);
  float* dec  = (float*)(ws + DEC_OFF);
  float* part = (float*)(ws + PART_OFF);
  float* at   = (float*)(ws + AT_OFF);

  prep_ws<<<2113, 256, 0, stream>>>(prev_s, s_t, W_prev, out, Aq, Bq);
  dec_kernel<<<256, 256, 0, stream>>>(s_t, W_s, b_s, dec);
  score_gemm<<<2048, 256, 0, stream>>>(Aq, Bq, dec, v, part);
  softmax_kernel<<<64, 256, 0, stream>>>(part, at);
  ctd_ws<<<512, 256, 0, stream>>>(Aq, at, out);
}